// Round 7
// baseline (530.567 us; speedup 1.0000x reference)
//
#include <hip/hip_runtime.h>

// out[b,o] = sum_g as[b,g]*ws[o,g]*dot(x4[b,g*128..],w4[o,..]) + bias[o]
// B=4096, O=11008, K=4096, GS=128, G=32. Inputs normalized by harness to f32.
// R11: occupancy doubling within the proven 128x128 envelope.
//      R4/R10 evidence: gemm runs at the SERIALIZED sum of MFMA(1152cy) +
//      VALU(768cy) per SIMD group-pair; 2 waves/SIMD barrier-locked in-phase
//      cannot co-issue pipes (MfmaUtil 27% == 573/2121). Source-order
//      interleave (R10) was neutral -> overlap needs MORE INDEPENDENT WAVES,
//      not reordering. This kernel: 512 threads / 8 waves per block, wave
//      tile 64x32 (facc[4][2]=32 regs, live ~110), so the 128-VGPR cap that
//      512-thread blocks get (R3 finding) now FITS -> 4 waves/SIMD,
//      2 blocks/CU (LDS 64KB x2), 16 waves/CU. Sync skeleton, swizzle,
//      staging identical to R4/R10 (per-group __syncthreads + full-group
//      prefetch in flight).

#define B_DIM 4096
#define O_DIM 11008
#define K_DIM 4096
#define G_NUM 32

#define NX32 8388608u    // int32 elements of xq
#define NW32 22544384u   // int32 elements of wq
#define X8_BYTES  16777216u
#define W8_BYTES  45088768u

typedef int   i32x4 __attribute__((ext_vector_type(4)));
typedef float f32x4 __attribute__((ext_vector_type(4)));

#define GLOAD16(src, dst) __builtin_amdgcn_global_load_lds(                      \
    (const __attribute__((address_space(1))) void*)(src),                        \
    (__attribute__((address_space(3))) void*)(dst), 16, 0, 0)

// ---------------- prepass 1: unpack nibbles -> signed int8 ----------------
__device__ __forceinline__ unsigned pack2(int v) {
    int t = v ^ 0x88;                                  // (q^8)-8 per nibble
    unsigned lo = (unsigned)(((t & 15) - 8) & 0xFF);
    unsigned hi = (unsigned)((((t >> 4) & 15) - 8) & 0xFF);
    return lo | (hi << 8);
}

__global__ __launch_bounds__(256)
void unpack_kernel(const int* __restrict__ xq, const int* __restrict__ wq,
                   unsigned char* __restrict__ X8, unsigned char* __restrict__ W8) {
    unsigned t = blockIdx.x * 256u + threadIdx.x;      // one thread: 8 int32 -> 16 B
    const int* src;
    unsigned char* dst;
    if (t < NX32 / 8) {
        src = xq + (size_t)t * 8;
        dst = X8 + (size_t)t * 16;
    } else {
        unsigned j = t - NX32 / 8;
        src = wq + (size_t)j * 8;
        dst = W8 + (size_t)j * 16;
    }
    int4 v0 = ((const int4*)src)[0];
    int4 v1 = ((const int4*)src)[1];
    uint4 o;
    o.x = pack2(v0.x) | (pack2(v0.y) << 16);
    o.y = pack2(v0.z) | (pack2(v0.w) << 16);
    o.z = pack2(v1.x) | (pack2(v1.y) << 16);
    o.w = pack2(v1.z) | (pack2(v1.w) << 16);
    *(uint4*)dst = o;
}

// ------------- prepass 2: coalesced LDS-tiled scale transpose -------------
__global__ __launch_bounds__(256)
void tscale_kernel(const float* __restrict__ as_, const float* __restrict__ ws_,
                   float* __restrict__ asT, float* __restrict__ wsT) {
    __shared__ float tile[64][33];
    const int blk = blockIdx.x, t = threadIdx.x;
    const float* src; float* dst; int R0, RTOT;
    if (blk < 64) { src = as_; dst = asT; R0 = blk * 64;        RTOT = B_DIM; }
    else          { src = ws_; dst = wsT; R0 = (blk - 64) * 64; RTOT = O_DIM; }
    {
        const int r = t >> 2, cc = (t & 3) * 8;
        const float* p = src + (size_t)(R0 + r) * G_NUM + cc;
        f32x4 v0 = *(const f32x4*)p;
        f32x4 v1 = *(const f32x4*)(p + 4);
#pragma unroll
        for (int k = 0; k < 4; ++k) { tile[r][cc + k] = v0[k]; tile[r][cc + 4 + k] = v1[k]; }
    }
    __syncthreads();
    {
        const int g = t >> 3, bc = (t & 7) * 8;
        f32x4 w0, w1;
#pragma unroll
        for (int k = 0; k < 4; ++k) { w0[k] = tile[bc + k][g]; w1[k] = tile[bc + 4 + k][g]; }
        float* q = dst + (size_t)g * RTOT + R0 + bc;
        *(f32x4*)q = w0;
        *(f32x4*)(q + 4) = w1;
    }
}

// ---------------- GEMM: 128x128 tile, 512 threads, 8 waves ----------------
__global__ __launch_bounds__(512, 2)
void gemm_i8(const unsigned char* __restrict__ X8, const unsigned char* __restrict__ W8,
             const float* __restrict__ asT, const float* __restrict__ wsT,
             const float* __restrict__ bias, float* __restrict__ out) {
    __shared__ __align__(16) unsigned char A0[16384];
    __shared__ __align__(16) unsigned char B0[16384];
    __shared__ __align__(16) unsigned char A1[16384];
    __shared__ __align__(16) unsigned char B1[16384];

    const int tid  = threadIdx.x;
    const int wv   = tid >> 6;             // 0..7
    const int lane = tid & 63;
    const int quad = lane >> 4;
    const int lq   = lane & 15;
    const int bm   = blockIdx.x;
    const int bn   = blockIdx.y;
    const int wm   = (wv & 1) << 6;        // 0 / 64
    const int wn   = (wv >> 1) << 5;       // 0 / 32 / 64 / 96

    f32x4 facc[4][2] = {};

    const int l8 = lane >> 3;
    const int c8 = lane & 7;
    const int sw_chunk = ((c8 ^ l8) << 4);            // XOR store-side swizzle
    const size_t xrow0 = (size_t)(bm * 128) * K_DIM;
    const size_t wrow0 = (size_t)(bn * 128) * K_DIM;
    const int abase = bm * 128 + wm + (quad << 2);
    const int wbase = bn * 128 + wn + lq;
    const int pa0 = ((quad ^ (lq & 7)) << 4);
    const int pa1 = (((4 + quad) ^ (lq & 7)) << 4);

    auto stage = [&](int g, unsigned char* Ad, unsigned char* Bd) {
        const int gb = g << 7;
#pragma unroll
        for (int s = 0; s < 2; ++s) {
            const int slab = (wv << 1) + s;           // 0..15
            const int row  = (slab << 3) + l8;        // 0..127
            const unsigned char* gpA = X8 + xrow0 + (size_t)row * K_DIM + gb + sw_chunk;
            const unsigned char* gpB = W8 + wrow0 + (size_t)row * K_DIM + gb + sw_chunk;
            GLOAD16(gpA, Ad + (slab << 10));
            GLOAD16(gpB, Bd + (slab << 10));
        }
    };

    auto compute = [&](int g, const unsigned char* Ab, const unsigned char* Bb) {
        // scales: issued now, consumed after the first MFMA cluster
        f32x4 asr[4];
        float wsn[2];
#pragma unroll
        for (int i = 0; i < 4; ++i)
            asr[i] = *(const f32x4*)&asT[(g << 12) + abase + (i << 4)];
#pragma unroll
        for (int j = 0; j < 2; ++j)
            wsn[j] = wsT[(size_t)g * O_DIM + wbase + (j << 4)];

        // B fragments (live across the i-loop)
        i32x4 bv0[2], bv1[2];
#pragma unroll
        for (int j = 0; j < 2; ++j) {
            bv0[j] = *(const i32x4*)&Bb[((wn + (j << 4) + lq) << 7) + pa0];
            bv1[j] = *(const i32x4*)&Bb[((wn + (j << 4) + lq) << 7) + pa1];
        }
        // preload i=0 A fragments
        i32x4 a0c = *(const i32x4*)&Ab[((wm + lq) << 7) + pa0];
        i32x4 a1c = *(const i32x4*)&Ab[((wm + lq) << 7) + pa1];

#pragma unroll
        for (int i = 0; i < 4; ++i) {
            const i32x4 a0 = a0c, a1 = a1c;
            if (i < 3) {                    // prefetch next i-row under MFMA
                a0c = *(const i32x4*)&Ab[((wm + ((i + 1) << 4) + lq) << 7) + pa0];
                a1c = *(const i32x4*)&Ab[((wm + ((i + 1) << 4) + lq) << 7) + pa1];
            }
            i32x4 q[2];
#pragma unroll
            for (int j = 0; j < 2; ++j)
                q[j] = __builtin_amdgcn_mfma_i32_16x16x64_i8(a0, bv0[j], (i32x4){0, 0, 0, 0}, 0, 0, 0);
#pragma unroll
            for (int j = 0; j < 2; ++j)
                q[j] = __builtin_amdgcn_mfma_i32_16x16x64_i8(a1, bv1[j], q[j], 0, 0, 0);
            // immediate rescale (independent of i+1's MFMAs)
#pragma unroll
            for (int j = 0; j < 2; ++j) {
                const f32x4 s = asr[i] * wsn[j];
                f32x4 gf;
#pragma unroll
                for (int r = 0; r < 4; ++r) gf[r] = (float)q[j][r];
                facc[i][j] += gf * s;
            }
        }
    };

    stage(0, A0, B0);

    for (int g2 = 0; g2 < G_NUM; g2 += 2) {
        __syncthreads();                     // drains stage(g2) — issued a full phase ago
        stage(g2 + 1, A1, B1);               // flies during compute(g2)
        compute(g2, A0, B0);

        __syncthreads();                     // drains stage(g2+1) — issued a phase ago
        if (g2 + 2 < G_NUM) stage(g2 + 2, A0, B0);
        compute(g2 + 1, A1, B1);
    }

    // epilogue (f32 output); C/D: col=lq, row=quad*4+r
    const int n0 = bn * 128 + wn + lq;
    const int m0 = bm * 128 + wm + (quad << 2);
    float bvs[2];
#pragma unroll
    for (int j = 0; j < 2; ++j) bvs[j] = bias[n0 + (j << 4)];
#pragma unroll
    for (int i = 0; i < 4; ++i) {
#pragma unroll
        for (int r = 0; r < 4; ++r) {
            float* orow = out + (size_t)(m0 + (i << 4) + r) * O_DIM;
#pragma unroll
            for (int j = 0; j < 2; ++j)
                orow[n0 + (j << 4)] = facc[i][j][r] + bvs[j];
        }
    }
}

extern "C" void kernel_launch(void* const* d_in, const int* in_sizes, int n_in,
                              void* d_out, int out_size, void* d_ws, size_t ws_size,
                              hipStream_t stream) {
    const int*   xq   = (const int*)d_in[0];
    const float* as_  = (const float*)d_in[1];
    const int*   wq   = (const int*)d_in[2];
    const float* ws_  = (const float*)d_in[3];
    const float* bias = (const float*)d_in[4];
    float* out        = (float*)d_out;

    unsigned char* X8 = (unsigned char*)d_ws;
    unsigned char* W8 = X8 + X8_BYTES;
    float* asT = (float*)((unsigned char*)d_ws + X8_BYTES + W8_BYTES);
    float* wsT = asT + (size_t)G_NUM * B_DIM;

    unpack_kernel<<<(NX32 + NW32) / 8 / 256, 256, 0, stream>>>(xq, wq, X8, W8);
    tscale_kernel<<<64 + 172, 256, 0, stream>>>(as_, ws_, asT, wsT);
    gemm_i8<<<dim3(B_DIM / 128, O_DIM / 128), 512, 0, stream>>>(X8, W8, asT, wsT, bias, out);
}

// Round 8
// 524.246 us; speedup vs baseline: 1.0121x; 1.0121x over previous
//
#include <hip/hip_runtime.h>

// out[b,o] = sum_g as[b,g]*ws[o,g]*dot(x4[b,g*128..],w4[o,..]) + bias[o]
// B=4096, O=11008, K=4096, GS=128, G=32. Inputs normalized by harness to f32.
// R12: attack the VALU (the real floor). Counter-derived model: i8 MFMA is
//      ~9cy/inst (573cy/group/SIMD, 27% util); rescale VALU is 933cy; stall
//      617; pipes ADDITIVE across R4/R10/R11 variants. Changes vs R10:
//      (1) packed-f32 rescale (f32x2 -> v_pk_mul/v_pk_fma): 192->128 ops;
//      (2) persistent zero i32x4 Z as MFMA C-operand (kills 16 accvgpr
//          zero-writes per row);
//      (3) row-pipelined compute with sched_group_barrier {1 MFMA, 4 VALU}:
//          row i's 8 MFMAs interleave with row i-1's 32 rescale ops
//          (independent: qA/qB ping-pong), so matrix pipe stays fed during
//          VALU instead of alternating. Named groups match actuals exactly
//          (ds 16, mfma 32, valu 96; row-3 tail rescale unnamed).
//      Envelope unchanged: 128x128 tile, 256 thr, dim3(32,86), 64KB dbuf LDS,
//      per-group __syncthreads + full-group prefetch in flight.

#define B_DIM 4096
#define O_DIM 11008
#define K_DIM 4096
#define G_NUM 32

#define NX32 8388608u    // int32 elements of xq
#define NW32 22544384u   // int32 elements of wq
#define X8_BYTES  16777216u
#define W8_BYTES  45088768u

typedef int   i32x4 __attribute__((ext_vector_type(4)));
typedef float f32x4 __attribute__((ext_vector_type(4)));
typedef float f32x2 __attribute__((ext_vector_type(2)));

#define GLOAD16(src, dst) __builtin_amdgcn_global_load_lds(                      \
    (const __attribute__((address_space(1))) void*)(src),                        \
    (__attribute__((address_space(3))) void*)(dst), 16, 0, 0)

#define SGB(mask, n) __builtin_amdgcn_sched_group_barrier((mask), (n), 0)

// ---------------- prepass 1: unpack nibbles -> signed int8 ----------------
__device__ __forceinline__ unsigned pack2(int v) {
    int t = v ^ 0x88;                                  // (q^8)-8 per nibble
    unsigned lo = (unsigned)(((t & 15) - 8) & 0xFF);
    unsigned hi = (unsigned)((((t >> 4) & 15) - 8) & 0xFF);
    return lo | (hi << 8);
}

__global__ __launch_bounds__(256)
void unpack_kernel(const int* __restrict__ xq, const int* __restrict__ wq,
                   unsigned char* __restrict__ X8, unsigned char* __restrict__ W8) {
    unsigned t = blockIdx.x * 256u + threadIdx.x;      // one thread: 8 int32 -> 16 B
    const int* src;
    unsigned char* dst;
    if (t < NX32 / 8) {
        src = xq + (size_t)t * 8;
        dst = X8 + (size_t)t * 16;
    } else {
        unsigned j = t - NX32 / 8;
        src = wq + (size_t)j * 8;
        dst = W8 + (size_t)j * 16;
    }
    int4 v0 = ((const int4*)src)[0];
    int4 v1 = ((const int4*)src)[1];
    uint4 o;
    o.x = pack2(v0.x) | (pack2(v0.y) << 16);
    o.y = pack2(v0.z) | (pack2(v0.w) << 16);
    o.z = pack2(v1.x) | (pack2(v1.y) << 16);
    o.w = pack2(v1.z) | (pack2(v1.w) << 16);
    *(uint4*)dst = o;
}

// ------------- prepass 2: coalesced LDS-tiled scale transpose -------------
__global__ __launch_bounds__(256)
void tscale_kernel(const float* __restrict__ as_, const float* __restrict__ ws_,
                   float* __restrict__ asT, float* __restrict__ wsT) {
    __shared__ float tile[64][33];
    const int blk = blockIdx.x, t = threadIdx.x;
    const float* src; float* dst; int R0, RTOT;
    if (blk < 64) { src = as_; dst = asT; R0 = blk * 64;        RTOT = B_DIM; }
    else          { src = ws_; dst = wsT; R0 = (blk - 64) * 64; RTOT = O_DIM; }
    {
        const int r = t >> 2, cc = (t & 3) * 8;
        const float* p = src + (size_t)(R0 + r) * G_NUM + cc;
        f32x4 v0 = *(const f32x4*)p;
        f32x4 v1 = *(const f32x4*)(p + 4);
#pragma unroll
        for (int k = 0; k < 4; ++k) { tile[r][cc + k] = v0[k]; tile[r][cc + 4 + k] = v1[k]; }
    }
    __syncthreads();
    {
        const int g = t >> 3, bc = (t & 7) * 8;
        f32x4 w0, w1;
#pragma unroll
        for (int k = 0; k < 4; ++k) { w0[k] = tile[bc + k][g]; w1[k] = tile[bc + 4 + k][g]; }
        float* q = dst + (size_t)g * RTOT + R0 + bc;
        *(f32x4*)q = w0;
        *(f32x4*)(q + 4) = w1;
    }
}

// ---------------- GEMM ----------------
__global__ __launch_bounds__(256, 2)
void gemm_i8(const unsigned char* __restrict__ X8, const unsigned char* __restrict__ W8,
             const float* __restrict__ asT, const float* __restrict__ wsT,
             const float* __restrict__ bias, float* __restrict__ out) {
    __shared__ __align__(16) unsigned char A0[16384];
    __shared__ __align__(16) unsigned char B0[16384];
    __shared__ __align__(16) unsigned char A1[16384];
    __shared__ __align__(16) unsigned char B1[16384];

    const int tid  = threadIdx.x;
    const int wv   = tid >> 6;
    const int lane = tid & 63;
    const int quad = lane >> 4;
    const int lq   = lane & 15;
    const int bm   = blockIdx.x;
    const int bn   = blockIdx.y;
    const int wm   = (wv & 1) << 6;
    const int wn   = (wv >> 1) << 6;

    f32x2 facc[4][4][2] = {};
    const i32x4 Z = {0, 0, 0, 0};          // persistent zero C-operand

    const int l8 = lane >> 3;
    const int c8 = lane & 7;
    const int sw_chunk = ((c8 ^ l8) << 4);            // XOR store-side swizzle
    const size_t xrow0 = (size_t)(bm * 128) * K_DIM;
    const size_t wrow0 = (size_t)(bn * 128) * K_DIM;
    const int abase = bm * 128 + wm + (quad << 2);
    const int wbase = bn * 128 + wn + lq;
    const int pa0 = ((quad ^ (lq & 7)) << 4);
    const int pa1 = (((4 + quad) ^ (lq & 7)) << 4);

    auto stage = [&](int g, unsigned char* Ad, unsigned char* Bd) {
        const int gb = g << 7;
#pragma unroll
        for (int s = 0; s < 4; ++s) {
            const int slab = (wv << 2) + s;
            const int row  = (slab << 3) + l8;
            GLOAD16(X8 + xrow0 + (size_t)row * K_DIM + gb + sw_chunk, Ad + (slab << 10));
            GLOAD16(W8 + wrow0 + (size_t)row * K_DIM + gb + sw_chunk, Bd + (slab << 10));
        }
    };

    auto compute = [&](int g, const unsigned char* Ab, const unsigned char* Bb) {
        f32x4 asr[4];
        float wsn[4];
#pragma unroll
        for (int i = 0; i < 4; ++i)
            asr[i] = *(const f32x4*)&asT[(g << 12) + abase + (i << 4)];
#pragma unroll
        for (int j = 0; j < 4; ++j)
            wsn[j] = wsT[(size_t)g * O_DIM + wbase + (j << 4)];

        i32x4 bv0[4], bv1[4];
#pragma unroll
        for (int j = 0; j < 4; ++j) {
            bv0[j] = *(const i32x4*)&Bb[((wn + (j << 4) + lq) << 7) + pa0];
            bv1[j] = *(const i32x4*)&Bb[((wn + (j << 4) + lq) << 7) + pa1];
        }

        i32x4 qA[4], qB[4];

        // packed rescale of one i-row from its q buffer (32 VALU ops)
        auto resc = [&](int i, const i32x4 (&q)[4]) {
#pragma unroll
            for (int j = 0; j < 4; ++j)
#pragma unroll
                for (int p = 0; p < 2; ++p) {
                    f32x2 d;
                    d[0] = (float)q[j][(p << 1)];
                    d[1] = (float)q[j][(p << 1) + 1];
                    f32x2 sa;
                    sa[0] = asr[i][(p << 1)];
                    sa[1] = asr[i][(p << 1) + 1];
                    const f32x2 s = sa * wsn[j];
                    facc[i][j][p] += s * d;          // v_pk_fma_f32
                }
        };

        i32x4 a0_0 = *(const i32x4*)&Ab[((wm +  0 + lq) << 7) + pa0];
        i32x4 a1_0 = *(const i32x4*)&Ab[((wm +  0 + lq) << 7) + pa1];
        i32x4 a0_1 = *(const i32x4*)&Ab[((wm + 16 + lq) << 7) + pa0];
        i32x4 a1_1 = *(const i32x4*)&Ab[((wm + 16 + lq) << 7) + pa1];

        // ---- row 0: MFMA only ----
#pragma unroll
        for (int j = 0; j < 4; ++j)
            qA[j] = __builtin_amdgcn_mfma_i32_16x16x64_i8(a0_0, bv0[j], Z, 0, 0, 0);
#pragma unroll
        for (int j = 0; j < 4; ++j)
            qA[j] = __builtin_amdgcn_mfma_i32_16x16x64_i8(a1_0, bv1[j], qA[j], 0, 0, 0);
        i32x4 a0_2 = *(const i32x4*)&Ab[((wm + 32 + lq) << 7) + pa0];
        i32x4 a1_2 = *(const i32x4*)&Ab[((wm + 32 + lq) << 7) + pa1];
        SGB(0x100, 12);                    // bv(8) + row0/1 A-frags(4)
#pragma unroll
        for (int k = 0; k < 8; ++k) SGB(0x8, 1);

        // ---- row 1: MFMA(row1) interleaved with rescale(row0) ----
#pragma unroll
        for (int j = 0; j < 4; ++j)
            qB[j] = __builtin_amdgcn_mfma_i32_16x16x64_i8(a0_1, bv0[j], Z, 0, 0, 0);
#pragma unroll
        for (int j = 0; j < 4; ++j)
            qB[j] = __builtin_amdgcn_mfma_i32_16x16x64_i8(a1_1, bv1[j], qB[j], 0, 0, 0);
        resc(0, qA);
        i32x4 a0_3 = *(const i32x4*)&Ab[((wm + 48 + lq) << 7) + pa0];
        i32x4 a1_3 = *(const i32x4*)&Ab[((wm + 48 + lq) << 7) + pa1];
        SGB(0x100, 2);                     // row2 A-frags
#pragma unroll
        for (int k = 0; k < 8; ++k) { SGB(0x8, 1); SGB(0x2, 4); }

        // ---- row 2: MFMA(row2) interleaved with rescale(row1) ----
#pragma unroll
        for (int j = 0; j < 4; ++j)
            qA[j] = __builtin_amdgcn_mfma_i32_16x16x64_i8(a0_2, bv0[j], Z, 0, 0, 0);
#pragma unroll
        for (int j = 0; j < 4; ++j)
            qA[j] = __builtin_amdgcn_mfma_i32_16x16x64_i8(a1_2, bv1[j], qA[j], 0, 0, 0);
        resc(1, qB);
        SGB(0x100, 2);                     // row3 A-frags
#pragma unroll
        for (int k = 0; k < 8; ++k) { SGB(0x8, 1); SGB(0x2, 4); }

        // ---- row 3: MFMA(row3) interleaved with rescale(row2) ----
#pragma unroll
        for (int j = 0; j < 4; ++j)
            qB[j] = __builtin_amdgcn_mfma_i32_16x16x64_i8(a0_3, bv0[j], Z, 0, 0, 0);
#pragma unroll
        for (int j = 0; j < 4; ++j)
            qB[j] = __builtin_amdgcn_mfma_i32_16x16x64_i8(a1_3, bv1[j], qB[j], 0, 0, 0);
        resc(2, qA);
#pragma unroll
        for (int k = 0; k < 8; ++k) { SGB(0x8, 1); SGB(0x2, 4); }

        // ---- tail: rescale row 3 (overlaps next stage issue / barrier) ----
        resc(3, qB);
    };

    stage(0, A0, B0);

    for (int g2 = 0; g2 < G_NUM; g2 += 2) {
        __syncthreads();                     // drains stage(g2) — issued a full phase ago
        stage(g2 + 1, A1, B1);               // flies during compute(g2)
        compute(g2, A0, B0);

        __syncthreads();                     // drains stage(g2+1) — issued a phase ago
        if (g2 + 2 < G_NUM) stage(g2 + 2, A0, B0);
        compute(g2 + 1, A1, B1);
    }

    // epilogue (f32 output); C/D: col=lq, row=quad*4+r, r=(p<<1)+e
    const int n0 = bn * 128 + wn + lq;
    const int m0 = bm * 128 + wm + (quad << 2);
    float bvs[4];
#pragma unroll
    for (int j = 0; j < 4; ++j) bvs[j] = bias[n0 + (j << 4)];
#pragma unroll
    for (int i = 0; i < 4; ++i) {
#pragma unroll
        for (int p = 0; p < 2; ++p)
#pragma unroll
            for (int e = 0; e < 2; ++e) {
                const int r = (p << 1) + e;
                float* orow = out + (size_t)(m0 + (i << 4) + r) * O_DIM;
#pragma unroll
                for (int j = 0; j < 4; ++j)
                    orow[n0 + (j << 4)] = facc[i][j][p][e] + bvs[j];
            }
    }
}

extern "C" void kernel_launch(void* const* d_in, const int* in_sizes, int n_in,
                              void* d_out, int out_size, void* d_ws, size_t ws_size,
                              hipStream_t stream) {
    const int*   xq   = (const int*)d_in[0];
    const float* as_  = (const float*)d_in[1];
    const int*   wq   = (const int*)d_in[2];
    const float* ws_  = (const float*)d_in[3];
    const float* bias = (const float*)d_in[4];
    float* out        = (float*)d_out;

    unsigned char* X8 = (unsigned char*)d_ws;
    unsigned char* W8 = X8 + X8_BYTES;
    float* asT = (float*)((unsigned char*)d_ws + X8_BYTES + W8_BYTES);
    float* wsT = asT + (size_t)G_NUM * B_DIM;

    unpack_kernel<<<(NX32 + NW32) / 8 / 256, 256, 0, stream>>>(xq, wq, X8, W8);
    tscale_kernel<<<64 + 172, 256, 0, stream>>>(as_, ws_, asT, wsT);
    gemm_i8<<<dim3(B_DIM / 128, O_DIM / 128), 256, 0, stream>>>(X8, W8, asT, wsT, bias, out);
}